// Round 3
// baseline (163.942 us; speedup 1.0000x reference)
//
#include <hip/hip_runtime.h>

#define IMG     256
#define NIMG    384                    // B*C = 128*3
#define STEPS   64
#define ROWS_PT 32                     // rows per thread
#define STRIPS  4                      // one strip per wave
#define ROWS_PB (ROWS_PT * STRIPS)     // 128 rows per block
#define BANDS   (IMG / ROWS_PB)        // 2 blocks per image
#define INFV    1e30f

// bin = clip(ceil((v-0.02)/RES), 0, 63); fused form ceil(v*63/0.96 - 1.3125).
// Differs from the reference's exact f32 divide only on ~ULP bin-boundary
// values; absmax tolerance (174) absorbs that. Saves the ~12-op f32 div seq.
__device__ __forceinline__ int bin_of(float v) {
    int t = (int)ceilf(__builtin_fmaf(v, 65.625f, -1.3125f));
    t = t < 0 ? 0 : t;
    return t > 63 ? 63 : t;
}

// Load 6-wide window (cols col0-1 .. col0+4) of row r; +inf outside image.
__device__ __forceinline__ void load_row(const float* __restrict__ base,
                                         int r, int col0, float w[6]) {
    if ((unsigned)r >= IMG) {
        w[0] = w[1] = w[2] = w[3] = w[4] = w[5] = INFV;
        return;
    }
    const float* p = base + r * IMG + col0;
    float4 q = *(const float4*)p;              // col0 % 4 == 0 -> aligned
    w[1] = q.x; w[2] = q.y; w[3] = q.z; w[4] = q.w;
    w[0] = (col0 > 0)       ? p[-1] : INFV;    // L1 hit (neighbor's line)
    w[5] = (col0 + 4 < IMG) ? p[4]  : INFV;
}

// Max-vertex attribution: each cell (vertex/edge/square) is attributed to its
// (value, index)-max corner; all cells owned by a pixel share its filtration
// -> one integer LDS-histogram add per pixel. Rolling 3-row register window,
// next row software-pipelined one iteration ahead. Per-block histogram slot
// written with plain stores (no global atomics, no memset kernel needed).
__global__ __launch_bounds__(256) void ecc_main(const float* __restrict__ x,
                                                int* __restrict__ hist) {
    const int img   = blockIdx.x / BANDS;
    const int band  = blockIdx.x % BANDS;
    const int lane  = threadIdx.x & 63;
    const int strip = threadIdx.x >> 6;        // == wave id
    const int col0  = lane * 4;
    const int r0    = band * ROWS_PB + strip * ROWS_PT;

    __shared__ int lh[STRIPS][STEPS];          // per-wave sub-histograms
    ((int*)lh)[threadIdx.x] = 0;               // 4*64 == 256
    __syncthreads();

    const float* base = x + (size_t)img * (IMG * IMG);

    float u[6], c[6], d[6], n[6];
    load_row(base, r0 - 1, col0, u);
    load_row(base, r0,     col0, c);
    load_row(base, r0 + 1, col0, d);

    for (int k = 0; k < ROWS_PT; ++k) {
        load_row(base, r0 + k + 2, col0, n);   // prefetch: not used this iter
#pragma unroll
        for (int i = 1; i <= 4; ++i) {
            float cv = c[i];
            if (cv <= 0.98f) {                 // reference T_MAX mask
                // neighbor with larger linear idx beats p iff vq >= vp;
                // smaller idx beats p iff vq > vp.
                bool oR = (c[i + 1] <  cv);
                bool oL = (c[i - 1] <= cv);
                bool oD = (d[i]     <  cv);
                bool oU = (u[i]     <= cv);
                bool sDR = oR & oD & (d[i + 1] <  cv);
                bool sDL = oL & oD & (d[i - 1] <  cv);
                bool sUR = oU & oR & (u[i + 1] <= cv);
                bool sUL = oU & oL & (u[i - 1] <= cv);
                int contrib = 1 - ((int)oR + (int)oL + (int)oD + (int)oU)
                                + ((int)sDR + (int)sDL + (int)sUR + (int)sUL);
                if (contrib) atomicAdd(&lh[strip][bin_of(cv)], contrib);
            }
        }
#pragma unroll
        for (int i = 0; i < 6; ++i) { u[i] = c[i]; c[i] = d[i]; d[i] = n[i]; }
    }

    __syncthreads();
    if (threadIdx.x < STEPS) {
        int t = threadIdx.x;
        // plain store to this block's private slot (d_ws is 0xAA-poisoned:
        // must write unconditionally, including zeros)
        hist[blockIdx.x * STEPS + t] = lh[0][t] + lh[1][t] + lh[2][t] + lh[3][t];
    }
}

// One wave64 per image: sum the band histograms, inclusive shfl scan, f32 out.
__global__ __launch_bounds__(64) void ecc_scan(const int* __restrict__ hist,
                                               float* __restrict__ out) {
    const int img = blockIdx.x;
    const int t   = threadIdx.x;
    int v = hist[(img * BANDS + 0) * STEPS + t] + hist[(img * BANDS + 1) * STEPS + t];
#pragma unroll
    for (int s = 1; s < 64; s <<= 1) {
        int y = __shfl_up(v, s, 64);
        if (t >= s) v += y;
    }
    out[img * STEPS + t] = (float)v;
}

extern "C" void kernel_launch(void* const* d_in, const int* in_sizes, int n_in,
                              void* d_out, int out_size, void* d_ws, size_t ws_size,
                              hipStream_t stream) {
    const float* x = (const float*)d_in[0];
    float* out = (float*)d_out;
    int* hist = (int*)d_ws;                    // NIMG*BANDS*STEPS ints (192 KiB)

    ecc_main<<<dim3(NIMG * BANDS), dim3(256), 0, stream>>>(x, hist);
    ecc_scan<<<dim3(NIMG), dim3(64), 0, stream>>>(hist, out);
}

// Round 4
// 153.869 us; speedup vs baseline: 1.0655x; 1.0655x over previous
//
#include <hip/hip_runtime.h>

#define IMG     256
#define NIMG    384                    // B*C = 128*3
#define STEPS   64
#define ROWS_PW 8                      // rows per wave
#define WAVES   4
#define ROWS_PB (ROWS_PW * WAVES)      // 32 rows per block
#define BANDS   (IMG / ROWS_PB)        // 8 blocks per image -> 3072 blocks
#define INFV    1e30f

// bin = clip(ceil((v-0.02)/RES), 0, 63); fused form ceil(v*65.625 - 1.3125).
// Differs from the reference's f32 divide only on ~ULP bin-boundary values;
// absmax tolerance (174) absorbs that.
__device__ __forceinline__ int bin_of(float v) {
    int t = (int)ceilf(__builtin_fmaf(v, 65.625f, -1.3125f));
    t = t < 0 ? 0 : t;
    return t > 63 ? 63 : t;
}

// Max-vertex attribution: each cell (vertex/edge/square) is attributed to its
// (value, index)-max corner; all cells owned by a pixel share its filtration
// -> one integer LDS-histogram add per pixel.
// A wave's 64 lanes x 4 cols = one full 256-wide row, so the horizontal halo
// comes from cross-lane shfl of the single aligned float4 (lane 0/63 edges are
// real image borders -> INFV): exactly 1 VMEM instruction per row per thread.
__global__ __launch_bounds__(256) void ecc_main(const float* __restrict__ x,
                                                int* __restrict__ hist) {
    const int img  = blockIdx.x / BANDS;
    const int band = blockIdx.x % BANDS;
    const int lane = threadIdx.x & 63;
    const int wave = threadIdx.x >> 6;
    const int col0 = lane * 4;
    const int r0   = band * ROWS_PB + wave * ROWS_PW;

    __shared__ int lh[WAVES][STEPS];           // per-wave sub-histograms
    ((int*)lh)[threadIdx.x] = 0;               // 4*64 == 256
    __syncthreads();

    const float* base = x + (size_t)img * (IMG * IMG);

    auto load6 = [&](int r, float w[6]) {
        float4 q;
        if ((unsigned)r < IMG) q = *(const float4*)(base + r * IMG + col0);
        else                   q = make_float4(INFV, INFV, INFV, INFV);
        w[1] = q.x; w[2] = q.y; w[3] = q.z; w[4] = q.w;
        float left  = __shfl_up(q.w, 1, 64);   // lane-1's last element
        float right = __shfl_down(q.x, 1, 64); // lane+1's first element
        w[0] = (lane == 0)  ? INFV : left;     // lane 0 is the image's col 0
        w[5] = (lane == 63) ? INFV : right;    // lane 63 ends at col 255
    };

    float u[6], c[6], d[6], n[6];
    load6(r0 - 1, u);
    load6(r0,     c);
    load6(r0 + 1, d);

#pragma unroll
    for (int k = 0; k < ROWS_PW; ++k) {
        load6(r0 + k + 2, n);                  // prefetch (unused this iter)
#pragma unroll
        for (int i = 1; i <= 4; ++i) {
            float cv = c[i];
            if (cv <= 0.98f) {                 // reference T_MAX mask
                // neighbor with larger linear idx beats p iff vq >= vp;
                // smaller idx beats p iff vq > vp.
                bool oR = (c[i + 1] <  cv);
                bool oL = (c[i - 1] <= cv);
                bool oD = (d[i]     <  cv);
                bool oU = (u[i]     <= cv);
                bool sDR = oR & oD & (d[i + 1] <  cv);
                bool sDL = oL & oD & (d[i - 1] <  cv);
                bool sUR = oU & oR & (u[i + 1] <= cv);
                bool sUL = oU & oL & (u[i - 1] <= cv);
                int contrib = 1 - ((int)oR + (int)oL + (int)oD + (int)oU)
                                + ((int)sDR + (int)sDL + (int)sUR + (int)sUL);
                if (contrib) atomicAdd(&lh[wave][bin_of(cv)], contrib);
            }
        }
#pragma unroll
        for (int i = 0; i < 6; ++i) { u[i] = c[i]; c[i] = d[i]; d[i] = n[i]; }
    }

    __syncthreads();
    if (threadIdx.x < STEPS) {
        int t = threadIdx.x;
        // plain store to this block's private slot (d_ws is 0xAA-poisoned,
        // so write unconditionally, zeros included)
        hist[blockIdx.x * STEPS + t] = lh[0][t] + lh[1][t] + lh[2][t] + lh[3][t];
    }
}

// One wave64 per image: sum its 8 band histograms, inclusive shfl scan, f32 out.
__global__ __launch_bounds__(64) void ecc_scan(const int* __restrict__ hist,
                                               float* __restrict__ out) {
    const int img = blockIdx.x;
    const int t   = threadIdx.x;
    int v = 0;
#pragma unroll
    for (int b = 0; b < BANDS; ++b)
        v += hist[(img * BANDS + b) * STEPS + t];
#pragma unroll
    for (int s = 1; s < 64; s <<= 1) {
        int y = __shfl_up(v, s, 64);
        if (t >= s) v += y;
    }
    out[img * STEPS + t] = (float)v;
}

extern "C" void kernel_launch(void* const* d_in, const int* in_sizes, int n_in,
                              void* d_out, int out_size, void* d_ws, size_t ws_size,
                              hipStream_t stream) {
    const float* x = (const float*)d_in[0];
    float* out = (float*)d_out;
    int* hist = (int*)d_ws;                    // NIMG*BANDS*STEPS ints (768 KiB)

    ecc_main<<<dim3(NIMG * BANDS), dim3(256), 0, stream>>>(x, hist);
    ecc_scan<<<dim3(NIMG), dim3(64), 0, stream>>>(hist, out);
}

// Round 5
// 149.568 us; speedup vs baseline: 1.0961x; 1.0288x over previous
//
#include <hip/hip_runtime.h>

#define IMG     256
#define NIMG    384                    // B*C = 128*3
#define STEPS   64
#define ROWS_PW 8                      // rows per wave
#define WAVES   4
#define ROWS_PB (ROWS_PW * WAVES)      // 32 rows per block
#define BANDS   (IMG / ROWS_PB)        // 8 blocks per image -> 3072 blocks
#define NROWS   (ROWS_PW + 2)          // rows held in registers (with halo)
#define INFV    1e30f

// bin = clip(ceil((v-0.02)/RES), 0, 63); fused form ceil(v*65.625 - 1.3125).
// Differs from the reference's f32 divide only on ~ULP bin-boundary values;
// absmax tolerance (174) absorbs that.
__device__ __forceinline__ int bin_of(float v) {
    int t = (int)ceilf(__builtin_fmaf(v, 65.625f, -1.3125f));
    t = t < 0 ? 0 : t;
    return t > 63 ? 63 : t;
}

// Max-vertex attribution: each cell (vertex/edge/square) is attributed to its
// (value, index)-max corner; all cells owned by a pixel share its filtration
// -> one integer LDS-histogram add per pixel.
// Latency structure (the R4 lesson): issue ALL 10 row loads back-to-back into
// registers (single vmcnt drain per strip, not per row), THEN all halo
// shuffles (single lgkmcnt drain), THEN pure-VALU compute. One memory stall
// per 8 rows instead of eight.
__global__ __launch_bounds__(256) void ecc_main(const float* __restrict__ x,
                                                int* __restrict__ hist) {
    const int img  = blockIdx.x / BANDS;
    const int band = blockIdx.x % BANDS;
    const int lane = threadIdx.x & 63;
    const int wave = threadIdx.x >> 6;
    const int col0 = lane * 4;
    const int r0   = band * ROWS_PB + wave * ROWS_PW;

    __shared__ int lh[WAVES][STEPS];           // per-wave sub-histograms
    ((int*)lh)[threadIdx.x] = 0;               // 4*64 == 256
    __syncthreads();

    const float* base = x + (size_t)img * (IMG * IMG);

    // Stage 1: all row loads issued back-to-back (wave's 64 lanes x 4 cols
    // = one full 256-wide row -> exactly 1 VMEM instruction per row).
    float4 q[NROWS];
#pragma unroll
    for (int k = 0; k < NROWS; ++k) {
        int r = r0 - 1 + k;
        if ((unsigned)r < IMG) q[k] = *(const float4*)(base + r * IMG + col0);
        else                   q[k] = make_float4(INFV, INFV, INFV, INFV);
    }

    // Stage 2: horizontal halos via cross-lane shuffle of the float4 edges.
    // Lane 0 / lane 63 outer edges are true image borders -> INFV.
    float hl[NROWS], hr[NROWS];
#pragma unroll
    for (int k = 0; k < NROWS; ++k) {
        float lv = __shfl_up(q[k].w, 1, 64);
        float rv = __shfl_down(q[k].x, 1, 64);
        hl[k] = (lane == 0)  ? INFV : lv;
        hr[k] = (lane == 63) ? INFV : rv;
    }

    // Stage 3: pure-VALU ownership tests + one LDS atomic per pixel.
#pragma unroll
    for (int k = 1; k <= ROWS_PW; ++k) {
        float u[6], c[6], d[6];
        u[0] = hl[k-1]; u[1] = q[k-1].x; u[2] = q[k-1].y; u[3] = q[k-1].z; u[4] = q[k-1].w; u[5] = hr[k-1];
        c[0] = hl[k];   c[1] = q[k].x;   c[2] = q[k].y;   c[3] = q[k].z;   c[4] = q[k].w;   c[5] = hr[k];
        d[0] = hl[k+1]; d[1] = q[k+1].x; d[2] = q[k+1].y; d[3] = q[k+1].z; d[4] = q[k+1].w; d[5] = hr[k+1];
#pragma unroll
        for (int i = 1; i <= 4; ++i) {
            float cv = c[i];
            if (cv <= 0.98f) {                 // reference T_MAX mask
                // neighbor with larger linear idx beats p iff vq >= vp;
                // smaller idx beats p iff vq > vp.
                bool oR = (c[i + 1] <  cv);
                bool oL = (c[i - 1] <= cv);
                bool oD = (d[i]     <  cv);
                bool oU = (u[i]     <= cv);
                bool sDR = oR & oD & (d[i + 1] <  cv);
                bool sDL = oL & oD & (d[i - 1] <  cv);
                bool sUR = oU & oR & (u[i + 1] <= cv);
                bool sUL = oU & oL & (u[i - 1] <= cv);
                int contrib = 1 - ((int)oR + (int)oL + (int)oD + (int)oU)
                                + ((int)sDR + (int)sDL + (int)sUR + (int)sUL);
                if (contrib) atomicAdd(&lh[wave][bin_of(cv)], contrib);
            }
        }
    }

    __syncthreads();
    if (threadIdx.x < STEPS) {
        int t = threadIdx.x;
        // plain store to this block's private slot (d_ws is 0xAA-poisoned,
        // so write unconditionally, zeros included)
        hist[blockIdx.x * STEPS + t] = lh[0][t] + lh[1][t] + lh[2][t] + lh[3][t];
    }
}

// One wave64 per image: sum its 8 band histograms, inclusive shfl scan, f32 out.
__global__ __launch_bounds__(64) void ecc_scan(const int* __restrict__ hist,
                                               float* __restrict__ out) {
    const int img = blockIdx.x;
    const int t   = threadIdx.x;
    int v = 0;
#pragma unroll
    for (int b = 0; b < BANDS; ++b)
        v += hist[(img * BANDS + b) * STEPS + t];
#pragma unroll
    for (int s = 1; s < 64; s <<= 1) {
        int y = __shfl_up(v, s, 64);
        if (t >= s) v += y;
    }
    out[img * STEPS + t] = (float)v;
}

extern "C" void kernel_launch(void* const* d_in, const int* in_sizes, int n_in,
                              void* d_out, int out_size, void* d_ws, size_t ws_size,
                              hipStream_t stream) {
    const float* x = (const float*)d_in[0];
    float* out = (float*)d_out;
    int* hist = (int*)d_ws;                    // NIMG*BANDS*STEPS ints (768 KiB)

    ecc_main<<<dim3(NIMG * BANDS), dim3(256), 0, stream>>>(x, hist);
    ecc_scan<<<dim3(NIMG), dim3(64), 0, stream>>>(hist, out);
}

// Round 6
// 145.502 us; speedup vs baseline: 1.1267x; 1.0279x over previous
//
#include <hip/hip_runtime.h>

#define IMG     256
#define NIMG    384                    // B*C = 128*3
#define STEPS   64
#define ROWS_PW 8                      // rows per wave
#define WAVES   4
#define ROWS_PB (ROWS_PW * WAVES)      // 32 rows per block
#define BANDS   (IMG / ROWS_PB)        // 8 blocks per image -> 3072 blocks
#define NROWS   (ROWS_PW + 2)          // rows held in registers (with halo)
#define INFV    1e30f

// bin = clip(ceil((v-0.02)/RES), 0, 63); fused form ceil(v*65.625 - 1.3125).
// Differs from the reference's f32 divide only on ~ULP bin-boundary values;
// absmax tolerance (174) absorbs that.
__device__ __forceinline__ int bin_of(float v) {
    int t = (int)ceilf(__builtin_fmaf(v, 65.625f, -1.3125f));
    t = t < 0 ? 0 : t;
    return t > 63 ? 63 : t;
}

// Max-vertex attribution: each cell (vertex/edge/square) is attributed to its
// (value, index)-max corner; all cells owned by a pixel share its filtration
// -> one integer LDS-histogram add per pixel.
// R5 lesson kept: ALL row loads issued back-to-back (single vmcnt drain per
// wave). New in R6: (a) halo shuffles inlined per row (drops hl/hr register
// arrays -> lower VGPR, more waves/SIMD); (b) every cell-pair float compare
// is computed ONCE and reused complemented by the other endpoint pixel
// (total order: a<=b == !(b<a)) -- compares drop from 8 to ~4.75 per pixel.
__global__ __launch_bounds__(256) void ecc_main(const float* __restrict__ x,
                                                int* __restrict__ hist) {
    const int img  = blockIdx.x / BANDS;
    const int band = blockIdx.x % BANDS;
    const int lane = threadIdx.x & 63;
    const int wave = threadIdx.x >> 6;
    const int col0 = lane * 4;
    const int r0   = band * ROWS_PB + wave * ROWS_PW;

    __shared__ int lh[WAVES][STEPS];           // per-wave sub-histograms
    ((int*)lh)[threadIdx.x] = 0;               // 4*64 == 256
    __syncthreads();

    const float* base = x + (size_t)img * (IMG * IMG);

    // Stage 1: all row loads back-to-back (wave's 64 lanes x 4 cols = one
    // full 256-wide row -> exactly 1 VMEM instruction per row).
    float4 q[NROWS];
#pragma unroll
    for (int k = 0; k < NROWS; ++k) {
        int r = r0 - 1 + k;                    // wave-uniform bounds test
        if ((unsigned)r < IMG) q[k] = *(const float4*)(base + r * IMG + col0);
        else                   q[k] = make_float4(INFV, INFV, INFV, INFV);
    }

    auto halo = [&](int k, float& l, float& r) {
        float lv = __shfl_up(q[k].w, 1, 64);   // lane-1's last element
        float rv = __shfl_down(q[k].x, 1, 64); // lane+1's first element
        l = (lane == 0)  ? INFV : lv;          // lane 0 = image col 0
        r = (lane == 63) ? INFV : rv;          // lane 63 ends at col 255
    };

    // Carried up-row flags (window cols 1..4): pU[i]=(u[i]<=c[i]),
    // pUR[i]=(u[i+1]<=c[i]), pUL[i]=(u[i-1]<=c[i]).
    bool pU[5], pUR[5], pUL[5];
    float chl, chr;                            // halos of current c row
    {
        float uhl, uhr;
        halo(0, uhl, uhr);
        halo(1, chl, chr);
        float u[6] = {uhl, q[0].x, q[0].y, q[0].z, q[0].w, uhr};
        float c[6] = {chl, q[1].x, q[1].y, q[1].z, q[1].w, chr};
#pragma unroll
        for (int i = 1; i <= 4; ++i) {
            pU[i]  = (u[i]     <= c[i]);
            pUR[i] = (u[i + 1] <= c[i]);
            pUL[i] = (u[i - 1] <= c[i]);
        }
    }

#pragma unroll
    for (int k = 1; k <= ROWS_PW; ++k) {
        float dhl, dhr;
        halo(k + 1, dhl, dhr);
        float c[6] = {chl, q[k].x,     q[k].y,     q[k].z,     q[k].w,     chr};
        float d[6] = {dhl, q[k + 1].x, q[k + 1].y, q[k + 1].z, q[k + 1].w, dhr};

        bool eD[5], dDR[5], dDL[5], eR[5];
#pragma unroll
        for (int i = 1; i <= 4; ++i) {
            eD[i]  = (d[i]     < c[i]);        // p owns down edge
            dDR[i] = (d[i + 1] < c[i]);        // down-right diagonal compare
            dDL[i] = (d[i - 1] < c[i]);        // down-left  diagonal compare
            eR[i]  = (c[i + 1] < c[i]);        // p owns right edge
        }
        bool dDRm = (d[1] < c[0]);             // serves next row's pUL[1]
        bool dDLp = (d[4] < c[5]);             // serves next row's pUR[4]
        bool oLn  = (c[0] <= c[1]);            // oL for i=1

#pragma unroll
        for (int i = 1; i <= 4; ++i) {
            float cv = c[i];
            bool oR = eR[i], oL = oLn, oD = eD[i], oU = pU[i];
            bool sDR = oR & oD & dDR[i];
            bool sDL = oL & oD & dDL[i];
            bool sUR = oU & oR & pUR[i];
            bool sUL = oU & oL & pUL[i];
            int contrib = 1 - ((int)oR + (int)oL + (int)oD + (int)oU)
                            + ((int)sDR + (int)sDL + (int)sUR + (int)sUL);
            if (cv <= 0.98f && contrib)        // reference T_MAX mask
                atomicAdd(&lh[wave][bin_of(cv)], contrib);
            oLn = !eR[i];                      // oL(i+1) = !(c[i+1] < c[i])
        }

        // rotate: current down-compares become next row's up-flags (negated)
#pragma unroll
        for (int i = 1; i <= 4; ++i) pU[i] = !eD[i];
        pUR[1] = !dDL[2]; pUR[2] = !dDL[3]; pUR[3] = !dDL[4]; pUR[4] = !dDLp;
        pUL[1] = !dDRm;   pUL[2] = !dDR[1]; pUL[3] = !dDR[2]; pUL[4] = !dDR[3];
        chl = dhl; chr = dhr;
    }

    __syncthreads();
    if (threadIdx.x < STEPS) {
        int t = threadIdx.x;
        // plain store to this block's private slot (d_ws is 0xAA-poisoned,
        // so write unconditionally, zeros included)
        hist[blockIdx.x * STEPS + t] = lh[0][t] + lh[1][t] + lh[2][t] + lh[3][t];
    }
}

// One wave64 per image: sum its 8 band histograms, inclusive shfl scan, f32 out.
__global__ __launch_bounds__(64) void ecc_scan(const int* __restrict__ hist,
                                               float* __restrict__ out) {
    const int img = blockIdx.x;
    const int t   = threadIdx.x;
    int v = 0;
#pragma unroll
    for (int b = 0; b < BANDS; ++b)
        v += hist[(img * BANDS + b) * STEPS + t];
#pragma unroll
    for (int s = 1; s < 64; s <<= 1) {
        int y = __shfl_up(v, s, 64);
        if (t >= s) v += y;
    }
    out[img * STEPS + t] = (float)v;
}

extern "C" void kernel_launch(void* const* d_in, const int* in_sizes, int n_in,
                              void* d_out, int out_size, void* d_ws, size_t ws_size,
                              hipStream_t stream) {
    const float* x = (const float*)d_in[0];
    float* out = (float*)d_out;
    int* hist = (int*)d_ws;                    // NIMG*BANDS*STEPS ints (768 KiB)

    ecc_main<<<dim3(NIMG * BANDS), dim3(256), 0, stream>>>(x, hist);
    ecc_scan<<<dim3(NIMG), dim3(64), 0, stream>>>(hist, out);
}